// Round 1
// baseline (130.262 us; speedup 1.0000x reference)
//
#include <hip/hip_runtime.h>
#include <math.h>

#define HS 8
#define E 12
#define NH 4
#define HD 3
#define NA 20
#define KC 4

// Precomputed, batch-independent:
//   g_Wt[m*32+j]  = sum_i sc_w1[j][i] * ctx_w2[i][m]      (folded ctx_w2 into score layer)
//   g_abias[a*32+j] = sc_b1[j] + sc_w1[j][128:140]·arep[a] + sc_w1[j][0:128]·ctx_b2
__device__ float g_Wt[128 * 32];
__device__ float g_abias[NA * 32];

__global__ void precompute_kernel(const float* __restrict__ card_emb,
                                  const int* __restrict__ aci,
                                  const float* __restrict__ ctx_w2,
                                  const float* __restrict__ ctx_b2,
                                  const float* __restrict__ sc_w1,
                                  const float* __restrict__ sc_b1) {
    int t = blockIdx.x * blockDim.x + threadIdx.x;
    if (t < 128 * 32) {
        int m = t >> 5, j = t & 31;
        float s = 0.f;
        for (int i = 0; i < 128; ++i) s += sc_w1[j * 140 + i] * ctx_w2[i * 128 + m];
        g_Wt[t] = s;
    } else if (t < 128 * 32 + NA * 32) {
        int t2 = t - 128 * 32;
        int a = t2 >> 5, j = t2 & 31;
        float arep[E];
#pragma unroll
        for (int k2 = 0; k2 < E; ++k2) arep[k2] = 0.f;
        float cnt = 0.f;
#pragma unroll
        for (int c = 0; c < KC; ++c) {
            int idx = aci[a * KC + c];
            if (idx != 0) {
                cnt += 1.f;
#pragma unroll
                for (int k2 = 0; k2 < E; ++k2) arep[k2] += card_emb[idx * E + k2];
            }
        }
        float inv = 1.f / fmaxf(cnt, 1.f);
        float s = sc_b1[j];
#pragma unroll
        for (int k2 = 0; k2 < E; ++k2) s += sc_w1[j * 140 + 128 + k2] * (arep[k2] * inv);
        for (int i = 0; i < 128; ++i) s += sc_w1[j * 140 + i] * ctx_b2[i];
        g_abias[t2] = s;
    }
}

__global__ __launch_bounds__(256) void policy_kernel(
    const int* __restrict__ hand_cards, const float* __restrict__ game_state,
    const float* __restrict__ discard, const int* __restrict__ enemy_card,
    const int* __restrict__ hand_size, const int* __restrict__ num_valid,
    const float* __restrict__ card_emb, const float* __restrict__ enemy_emb,
    const float* __restrict__ in_w, const float* __restrict__ in_b,
    const float* __restrict__ out_w, const float* __restrict__ out_b,
    const float* __restrict__ gs_w1, const float* __restrict__ gs_b1,
    const float* __restrict__ gs_w2, const float* __restrict__ gs_b2,
    const float* __restrict__ dp_w1, const float* __restrict__ dp_b1,
    const float* __restrict__ dp_w2, const float* __restrict__ dp_b2,
    const float* __restrict__ ctx_w1, const float* __restrict__ ctx_b1,
    const float* __restrict__ sc_w2, const float* __restrict__ sc_b2,
    float* __restrict__ out, int Btot) {
    __shared__ __align__(16) float s_card[54 * E];
    __shared__ __align__(16) float s_enemy[54 * E];
    for (int i = threadIdx.x; i < 54 * E; i += 256) {
        s_card[i] = card_emb[i];
        s_enemy[i] = enemy_emb[i];
    }
    __syncthreads();
    int b = blockIdx.x * 256 + threadIdx.x;
    if (b >= Btot) return;

    // ---- hand attention ----
    int hc[HS];
    {
        const int4* hp = (const int4*)(hand_cards + (size_t)b * HS);
        int4 h0 = hp[0], h1 = hp[1];
        hc[0] = h0.x; hc[1] = h0.y; hc[2] = h0.z; hc[3] = h0.w;
        hc[4] = h1.x; hc[5] = h1.y; hc[6] = h1.z; hc[7] = h1.w;
    }
    float he[HS][E];
    const float4* sc4 = (const float4*)s_card;
#pragma unroll
    for (int p = 0; p < HS; ++p) {
        float4 a = sc4[hc[p] * 3 + 0];
        float4 b4 = sc4[hc[p] * 3 + 1];
        float4 c = sc4[hc[p] * 3 + 2];
        he[p][0] = a.x;  he[p][1] = a.y;  he[p][2] = a.z;  he[p][3] = a.w;
        he[p][4] = b4.x; he[p][5] = b4.y; he[p][6] = b4.z; he[p][7] = b4.w;
        he[p][8] = c.x;  he[p][9] = c.y;  he[p][10] = c.z; he[p][11] = c.w;
    }

    float attsum[E];
#pragma unroll
    for (int e = 0; e < E; ++e) attsum[e] = 0.f;

    const float scale = 0.5773502691896258f;  // 1/sqrt(3)
#pragma unroll
    for (int h = 0; h < NH; ++h) {
        float qh[HS][HD], kh[HS][HD], vh[HS][HD];
#pragma unroll
        for (int d = 0; d < HD; ++d) {
            int rq = h * HD + d;
            float wq[E], wk[E], wv[E];
#pragma unroll
            for (int j = 0; j < E; ++j) {
                wq[j] = in_w[rq * E + j];
                wk[j] = in_w[(E + rq) * E + j];
                wv[j] = in_w[(2 * E + rq) * E + j];
            }
            float bq = in_b[rq], bk = in_b[E + rq], bv = in_b[2 * E + rq];
#pragma unroll
            for (int p = 0; p < HS; ++p) {
                float aq = bq, ak = bk, av = bv;
#pragma unroll
                for (int j = 0; j < E; ++j) {
                    aq += he[p][j] * wq[j];
                    ak += he[p][j] * wk[j];
                    av += he[p][j] * wv[j];
                }
                qh[p][d] = aq; kh[p][d] = ak; vh[p][d] = av;
            }
        }
#pragma unroll
        for (int p = 0; p < HS; ++p) {
            float s[HS];
            float mx = -3.0e38f;
#pragma unroll
            for (int kk = 0; kk < HS; ++kk) {
                float t = (qh[p][0] * kh[kk][0] + qh[p][1] * kh[kk][1] +
                           qh[p][2] * kh[kk][2]) * scale;
                t = (hc[kk] != 0) ? t : -1.0e9f;
                s[kk] = t;
                mx = fmaxf(mx, t);
            }
            float sum = 0.f;
#pragma unroll
            for (int kk = 0; kk < HS; ++kk) {
                float ev = __expf(s[kk] - mx);
                s[kk] = ev;
                sum += ev;
            }
            float inv = 1.f / sum;
            float a0 = 0.f, a1 = 0.f, a2 = 0.f;
#pragma unroll
            for (int kk = 0; kk < HS; ++kk) {
                a0 += s[kk] * vh[kk][0];
                a1 += s[kk] * vh[kk][1];
                a2 += s[kk] * vh[kk][2];
            }
            attsum[h * HD + 0] += a0 * inv;
            attsum[h * HD + 1] += a1 * inv;
            attsum[h * HD + 2] += a2 * inv;
        }
    }

    float c36[36];
    {
        float invlen = 1.f / fmaxf((float)hand_size[b], 1.f);
#pragma unroll
        for (int i = 0; i < E; ++i) {
            float a = out_b[i] * 8.f;
#pragma unroll
            for (int e = 0; e < E; ++e) a += out_w[i * E + e] * attsum[e];
            c36[i] = a * invlen;
        }
    }
    {
        int ec = enemy_card[b];
        const float4* se4 = (const float4*)s_enemy;
        float4 a = se4[ec * 3 + 0], b4 = se4[ec * 3 + 1], c = se4[ec * 3 + 2];
        c36[12] = a.x;  c36[13] = a.y;  c36[14] = a.z;  c36[15] = a.w;
        c36[16] = b4.x; c36[17] = b4.y; c36[18] = b4.z; c36[19] = b4.w;
        c36[20] = c.x;  c36[21] = c.y;  c36[22] = c.z;  c36[23] = c.w;
    }
    // ---- game_state MLP ----
    {
        float x[12];
        const float4* gp = (const float4*)(game_state + (size_t)b * 12);
        float4 x0 = gp[0], x1 = gp[1], x2 = gp[2];
        x[0] = x0.x; x[1] = x0.y; x[2] = x0.z;  x[3] = x0.w;
        x[4] = x1.x; x[5] = x1.y; x[6] = x1.z;  x[7] = x1.w;
        x[8] = x2.x; x[9] = x2.y; x[10] = x2.z; x[11] = x2.w;
        float acc[6];
#pragma unroll
        for (int c = 0; c < 6; ++c) acc[c] = gs_b2[c];
        for (int jj = 0; jj < 64; ++jj) {
            float hsum = gs_b1[jj];
#pragma unroll
            for (int i = 0; i < 12; ++i) hsum += x[i] * gs_w1[jj * 12 + i];
            hsum = fmaxf(hsum, 0.f);
#pragma unroll
            for (int c = 0; c < 6; ++c) acc[c] += hsum * gs_w2[c * 64 + jj];
        }
#pragma unroll
        for (int c = 0; c < 6; ++c) c36[24 + c] = acc[c];
    }
    // ---- discard-pile MLP ----
    {
        float x[54];
        const float2* dp2 = (const float2*)(discard + (size_t)b * 54);
#pragma unroll
        for (int i = 0; i < 27; ++i) {
            float2 t = dp2[i];
            x[2 * i] = t.x;
            x[2 * i + 1] = t.y;
        }
        float acc[6];
#pragma unroll
        for (int c = 0; c < 6; ++c) acc[c] = dp_b2[c];
        for (int jj = 0; jj < 64; ++jj) {
            float hsum = dp_b1[jj];
#pragma unroll
            for (int i = 0; i < 54; ++i) hsum += x[i] * dp_w1[jj * 54 + i];
            hsum = fmaxf(hsum, 0.f);
#pragma unroll
            for (int c = 0; c < 6; ++c) acc[c] += hsum * dp_w2[c * 64 + jj];
        }
#pragma unroll
        for (int c = 0; c < 6; ++c) c36[30 + c] = acc[c];
    }
    // ---- ctx layer 1 fused with folded score-layer projection ----
    float u[32];
#pragma unroll
    for (int j = 0; j < 32; ++j) u[j] = 0.f;
    for (int m = 0; m < 128; ++m) {
        float hsum = ctx_b1[m];
#pragma unroll
        for (int i = 0; i < 36; ++i) hsum += c36[i] * ctx_w1[m * 36 + i];
        hsum = fmaxf(hsum, 0.f);
#pragma unroll
        for (int j = 0; j < 32; ++j) u[j] += hsum * g_Wt[m * 32 + j];
    }
    // ---- per-action scores ----
    int nva = num_valid[0];
    float b2 = sc_b2[0];
    float res[NA];
#pragma unroll
    for (int a = 0; a < NA; ++a) {
        float s = b2;
#pragma unroll
        for (int j = 0; j < 32; ++j) s += sc_w2[j] * fmaxf(u[j] + g_abias[a * 32 + j], 0.f);
        res[a] = (a < nva) ? s : -1.0e8f;
    }
    float4* op = (float4*)(out + (size_t)b * NA);
#pragma unroll
    for (int i = 0; i < 5; ++i)
        op[i] = make_float4(res[4 * i], res[4 * i + 1], res[4 * i + 2], res[4 * i + 3]);
}

extern "C" void kernel_launch(void* const* d_in, const int* in_sizes, int n_in,
                              void* d_out, int out_size, void* d_ws, size_t ws_size,
                              hipStream_t stream) {
    const int* hand_cards = (const int*)d_in[0];
    const float* game_state = (const float*)d_in[1];
    const float* discard = (const float*)d_in[2];
    const int* enemy_card = (const int*)d_in[3];
    const int* hand_size = (const int*)d_in[4];
    const int* aci = (const int*)d_in[5];
    const int* num_valid = (const int*)d_in[6];
    const float* card_emb = (const float*)d_in[7];
    const float* enemy_emb = (const float*)d_in[8];
    const float* in_w = (const float*)d_in[9];
    const float* in_b = (const float*)d_in[10];
    const float* out_w = (const float*)d_in[11];
    const float* out_b = (const float*)d_in[12];
    const float* gs_w1 = (const float*)d_in[13];
    const float* gs_b1 = (const float*)d_in[14];
    const float* gs_w2 = (const float*)d_in[15];
    const float* gs_b2 = (const float*)d_in[16];
    const float* dp_w1 = (const float*)d_in[17];
    const float* dp_b1 = (const float*)d_in[18];
    const float* dp_w2 = (const float*)d_in[19];
    const float* dp_b2 = (const float*)d_in[20];
    const float* ctx_w1 = (const float*)d_in[21];
    const float* ctx_b1 = (const float*)d_in[22];
    const float* ctx_w2 = (const float*)d_in[23];
    const float* ctx_b2 = (const float*)d_in[24];
    const float* sc_w1 = (const float*)d_in[25];
    const float* sc_b1 = (const float*)d_in[26];
    const float* sc_w2 = (const float*)d_in[27];
    const float* sc_b2 = (const float*)d_in[28];

    int B = in_sizes[0] / HS;

    precompute_kernel<<<19, 256, 0, stream>>>(card_emb, aci, ctx_w2, ctx_b2, sc_w1, sc_b1);
    policy_kernel<<<(B + 255) / 256, 256, 0, stream>>>(
        hand_cards, game_state, discard, enemy_card, hand_size, num_valid,
        card_emb, enemy_emb, in_w, in_b, out_w, out_b,
        gs_w1, gs_b1, gs_w2, gs_b2, dp_w1, dp_b1, dp_w2, dp_b2,
        ctx_w1, ctx_b1, sc_w2, sc_b2, (float*)d_out, B);
}